// Round 6
// baseline (188.148 us; speedup 1.0000x reference)
//
#include <hip/hip_runtime.h>
#include <cmath>

// ConvLSTM, two-phase:
//   Phase 1: xg = conv_same(x[:, ::-1], Wx), one parallel kernel.
//            LDS-staged: block = 8 rows x 128 cols of one (b,t) image;
//            stage 11 input rows (halo incl.) x 2 channels into LDS,
//            double-buffered over channel pairs. Edge rows zeroed at staging
//            -> select-free compute. Weights wave-uniform -> SGPR.
//   Phase 2: 16 sequential step kernels (h-conv + gates), ~BW-floor.
//
// x:  (B=8, T=16, C=16, H=128, W=128) f32
// Wx: (KH=4, KW=2, C=16, O=8) HWIO     idx = kh*256 + kw*128 + c*8 + o
// Wh: (KH=4, KW=2, F=2, O=8)
// out:(B, T, F=2, H, W) f32
// ws: xg (64 MiB, layout [t][b][o][h][w]) + c-state (1 MiB)

constexpr int B_ = 8;
constexpr int T_ = 16;
constexpr int C_ = 16;
constexpr int F_ = 2;
constexpr int O_ = 8;
constexpr int H_ = 128;
constexpr int W_ = 128;
constexpr int HW_ = H_ * W_;
constexpr int KH_ = 4;
constexpr int KW_ = 2;
constexpr int PX_ = 4;

constexpr int LROWS = 11;              // 8 output rows + 3 halo
constexpr int LW    = 132;             // row stride (floats); cols 128..131 scratch
constexpr int LTILE = LROWS * LW;      // 1452 floats per (buf, channel)
constexpr int NQ    = LROWS * 32;      // 352 float4 per channel tile
constexpr int NQ2   = 2 * NQ;          // 704 per channel pair

typedef float fv4 __attribute__((ext_vector_type(4)));

__device__ __forceinline__ float hsig(float z) {
    return fminf(fmaxf(0.2f * z + 0.5f, 0.0f), 1.0f);
}

__device__ __forceinline__ float ftanh(float x) {
    float e = __expf(2.0f * x);
    return fmaf(-2.0f, 1.0f / (e + 1.0f), 1.0f);
}

// grid: 2048 blocks x 256 thr; block = (b,t, 8-row slab); thread = 4 w-pixels.
__global__ __launch_bounds__(256, 4) void xg_kernel(
    const float* __restrict__ x,
    const float* __restrict__ Wx,
    float* __restrict__ xg)
{
    __shared__ float lds[2 * 2 * LTILE];   // [dbuf][chan][row*LW+col]

    // XCD-chunked swizzle (2048 % 8 == 0 -> bijective)
    int wid = (blockIdx.x & 7) * 256 + (blockIdx.x >> 3);

    int bt   = wid >> 4;            // 16 blocks per (b,t)
    int slab = wid & 15;
    int row0 = slab * 8;

    int tid  = threadIdx.x;
    int oh_l = tid >> 5;            // 0..7 local output row
    int q    = tid & 31;
    int ow4  = q << 2;

    int b    = bt >> 4;
    int trev = bt & 15;
    int t    = 15 - trev;

    const float* xs = x + (size_t)bt * C_ * HW_;
    bool cval = ow4 < (W_ - 4);

    // ---- prologue: stage channels 0,1 into buffer 0 ----
    #pragma unroll
    for (int k = 0; k < 3; ++k) {
        int j = tid + k * 256;
        if (j < NQ2) {
            int cf = j >= NQ;
            int jj = j - (cf ? NQ : 0);
            int r  = jj >> 5;
            int c4 = (jj & 31) << 2;
            int ih = row0 - 1 + r;
            bool v = (unsigned)ih < (unsigned)H_;
            fv4 d = *reinterpret_cast<const fv4*>(
                xs + (size_t)cf * HW_ + (v ? ih : 0) * W_ + c4);
            if (!v) d = (fv4)0.0f;
            *reinterpret_cast<fv4*>(&lds[cf * LTILE + r * LW + c4]) = d;
        }
    }
    __syncthreads();

    float acc[PX_][O_];
    #pragma unroll
    for (int p = 0; p < PX_; ++p)
        #pragma unroll
        for (int o = 0; o < O_; ++o) acc[p][o] = 0.0f;

    // ---- main loop over channel pairs ----
    for (int cc = 0; cc < C_; cc += 2) {
        int bsel = (cc >> 1) & 1;
        bool more = (cc + 2) < C_;

        // issue global loads for next pair (held in regs through compute)
        fv4 st[3];
        int soff[3];
        bool sval[3];
        if (more) {
            #pragma unroll
            for (int k = 0; k < 3; ++k) {
                int j = tid + k * 256;
                sval[k] = false;
                if (j < NQ2) {
                    int cf = j >= NQ;
                    int jj = j - (cf ? NQ : 0);
                    int r  = jj >> 5;
                    int c4 = (jj & 31) << 2;
                    int ih = row0 - 1 + r;
                    bool v = (unsigned)ih < (unsigned)H_;
                    st[k] = *reinterpret_cast<const fv4*>(
                        xs + (size_t)(cc + 2 + cf) * HW_ + (v ? ih : 0) * W_ + c4);
                    if (!v) st[k] = (fv4)0.0f;
                    soff[k] = ((1 - bsel) * 2 + cf) * LTILE + r * LW + c4;
                    sval[k] = true;
                }
            }
        }

        // compute 2 channels from buf bsel (select-free rows; weights uniform)
        #pragma unroll
        for (int cl = 0; cl < 2; ++cl) {
            int c = cc + cl;
            const float* lb = &lds[(bsel * 2 + cl) * LTILE];
            #pragma unroll
            for (int kh = 0; kh < KH_; ++kh) {
                const float* lr = lb + (oh_l + kh) * LW + ow4;
                fv4 a  = *reinterpret_cast<const fv4*>(lr);
                fv4 bb = *reinterpret_cast<const fv4*>(lr + 4);
                float x0 = a.x, x1 = a.y, x2 = a.z, x3 = a.w;
                float x4 = cval ? bb.x : 0.0f;
                const float* wp = Wx + kh * (KW_ * C_ * O_) + c * O_;
                #pragma unroll
                for (int o = 0; o < O_; ++o) {
                    float w0 = wp[o];             // kw = 0
                    float w1 = wp[C_ * O_ + o];   // kw = 1
                    acc[0][o] = fmaf(x0, w0, acc[0][o]);
                    acc[1][o] = fmaf(x1, w0, acc[1][o]);
                    acc[2][o] = fmaf(x2, w0, acc[2][o]);
                    acc[3][o] = fmaf(x3, w0, acc[3][o]);
                    acc[0][o] = fmaf(x1, w1, acc[0][o]);
                    acc[1][o] = fmaf(x2, w1, acc[1][o]);
                    acc[2][o] = fmaf(x3, w1, acc[2][o]);
                    acc[3][o] = fmaf(x4, w1, acc[3][o]);
                }
            }
        }

        // write staged pair, then barrier
        if (more) {
            #pragma unroll
            for (int k = 0; k < 3; ++k) {
                if (sval[k])
                    *reinterpret_cast<fv4*>(&lds[soff[k]]) = st[k];
            }
            __syncthreads();
        }
    }

    int oh = row0 + oh_l;
    float* dst = xg + (size_t)(t * B_ + b) * O_ * HW_ + oh * W_ + ow4;
    #pragma unroll
    for (int o = 0; o < O_; ++o) {
        fv4 s;
        s.x = acc[0][o]; s.y = acc[1][o]; s.z = acc[2][o]; s.w = acc[3][o];
        __builtin_nontemporal_store(s, reinterpret_cast<fv4*>(dst + o * HW_));
    }
}

// ---------------- Phase 2: sequential LSTM step ----------------
__global__ __launch_bounds__(256) void step_kernel(
    const float* __restrict__ xg,
    const float* __restrict__ Wh,
    float* __restrict__ out,
    float* __restrict__ cbuf,
    int t)
{
    int gid = blockIdx.x * 256 + threadIdx.x;   // B*HW = 131072
    int b   = gid >> 14;
    int pix = gid & (HW_ - 1);
    int oh  = pix >> 7;
    int ow  = pix & (W_ - 1);

    const float* xgp = xg + (size_t)(t * B_ + b) * O_ * HW_ + pix;
    float acc[O_];
    #pragma unroll
    for (int o = 0; o < O_; ++o)
        acc[o] = __builtin_nontemporal_load(xgp + o * HW_);

    bool cv  = (ow + 1) < W_;
    int  co1 = cv ? 1 : 0;

    if (t > 0) {
        const float* hs = out + (size_t)(b * T_ + (t - 1)) * F_ * HW_;
        #pragma unroll
        for (int kh = 0; kh < KH_; ++kh) {
            int ih  = oh + kh - 1;
            bool rv = (unsigned)ih < (unsigned)H_;
            int ihc = rv ? ih : 0;
            const float* hrow = hs + ihc * W_ + ow;
            const float* wb   = Wh + kh * (KW_ * F_ * O_);
            #pragma unroll
            for (int f = 0; f < F_; ++f) {
                float h0 = hrow[f * HW_];
                float h1 = hrow[f * HW_ + co1];
                h0 = rv ? h0 : 0.0f;
                h1 = (rv && cv) ? h1 : 0.0f;
                #pragma unroll
                for (int o = 0; o < O_; ++o) {
                    acc[o] = fmaf(h0, wb[f * O_ + o], acc[o]);
                    acc[o] = fmaf(h1, wb[F_ * O_ + f * O_ + o], acc[o]);
                }
            }
        }
    }

    size_t cidx = (size_t)b * F_ * HW_ + pix;
    float cp0 = 0.0f, cp1 = 0.0f;
    if (t > 0) { cp0 = cbuf[cidx]; cp1 = cbuf[cidx + HW_]; }

    float gi0 = hsig(acc[0]);
    float gi1 = hsig(acc[1]);
    float gf0 = hsig(acc[2]);
    float gf1 = hsig(acc[3]);
    float gg0 = ftanh(acc[4]);
    float gg1 = ftanh(acc[5]);
    float go0 = hsig(acc[6]);
    float go1 = hsig(acc[7]);

    float cn0 = gf0 * cp0 + gi0 * gg0;
    float cn1 = gf1 * cp1 + gi1 * gg1;
    cbuf[cidx]       = cn0;
    cbuf[cidx + HW_] = cn1;

    size_t oidx = (size_t)(b * T_ + t) * F_ * HW_ + pix;
    out[oidx]       = go0 * ftanh(cn0);
    out[oidx + HW_] = go1 * ftanh(cn1);
}

extern "C" void kernel_launch(void* const* d_in, const int* in_sizes, int n_in,
                              void* d_out, int out_size, void* d_ws, size_t ws_size,
                              hipStream_t stream) {
    const float* x  = (const float*)d_in[0];
    const float* Wx = (const float*)d_in[1];
    const float* Wh = (const float*)d_in[2];
    float* out  = (float*)d_out;

    float* xg   = (float*)d_ws;                                            // 64 MiB
    float* cbuf = (float*)((char*)d_ws + (size_t)64 * 1024 * 1024 + 1024); // 1 MiB

    int xg_blocks = (B_ * T_ * HW_ / PX_) / 256;   // 2048
    xg_kernel<<<xg_blocks, 256, 0, stream>>>(x, Wx, xg);

    int blocks = (B_ * HW_) / 256;                 // 512
    for (int t = 0; t < T_; ++t) {
        step_kernel<<<blocks, 256, 0, stream>>>(xg, Wh, out, cbuf, t);
    }
}